// Round 1
// baseline (790.680 us; speedup 1.0000x reference)
//
#include <hip/hip_runtime.h>
#include <stdint.h>

#define BB 16
#define CC 64
#define NN 65536
#define QQ 16

__device__ __forceinline__ unsigned keyify(float x) {
    unsigned u = __float_as_uint(x);
    // negative: ~u ; positive: u | 0x80000000  -> monotone in float order
    return u ^ ((unsigned)((int)u >> 31) | 0x80000000u);
}

__device__ __forceinline__ float unkeyify(unsigned k) {
    unsigned u = (k & 0x80000000u) ? (k ^ 0x80000000u) : ~k;
    return __uint_as_float(u);
}

// ---------------- Kernel T: transpose (B,N,C) f32 -> (B,C,N) sortable u32 ----------------
__global__ __launch_bounds__(256) void transpose_keyify(const float* __restrict__ x,
                                                        unsigned* __restrict__ xt) {
    __shared__ unsigned tile[64 * 65];   // [n_local][c], pad to 65 -> 2-way conflicts max
    int bid = blockIdx.x;
    int b   = bid >> 10;            // 1024 n-tiles per batch
    int n0  = (bid & 1023) << 6;
    int tid = threadIdx.x;

    int f   = tid & 15;             // float4 column (c/4)
    int row = tid >> 4;             // 0..15
    const float4* src = (const float4*)(x + ((size_t)b * NN + n0) * CC);
#pragma unroll
    for (int r = 0; r < 4; ++r) {
        int nl = row + r * 16;
        float4 v = src[nl * 16 + f];
        unsigned* t = &tile[nl * 65 + f * 4];
        t[0] = keyify(v.x); t[1] = keyify(v.y); t[2] = keyify(v.z); t[3] = keyify(v.w);
    }
    __syncthreads();

    int nf = tid & 15;              // n quad index
    int cq = tid >> 4;              // 0..15
    unsigned* dstbase = xt + (size_t)b * ((size_t)CC * NN) + n0;
#pragma unroll
    for (int r = 0; r < 4; ++r) {
        int c = cq + r * 16;
        uint4 o;
        o.x = tile[(nf * 4 + 0) * 65 + c];
        o.y = tile[(nf * 4 + 1) * 65 + c];
        o.z = tile[(nf * 4 + 2) * 65 + c];
        o.w = tile[(nf * 4 + 3) * 65 + c];
        *(uint4*)(dstbase + (size_t)c * NN + nf * 4) = o;
    }
}

// ---------------- Kernel S: 4-level radix select, register-resident data ----------------
// 1024 blocks (one per (b,c)), 1024 threads, 64 values/thread.
template <bool TRANSPOSED>
__global__ __launch_bounds__(1024) void radix_select(const unsigned* __restrict__ xt,
                                                     const float* __restrict__ x,
                                                     float* __restrict__ out) {
    __shared__ unsigned HIST[32 * 256];       // u32 counts, bucket-major
    __shared__ uint8_t  map1[256];            // byte1 -> bucket1 (255 = dead path)
    __shared__ uint8_t  map2[32 * 256];       // (bucket1,byte2) -> bucket2
    __shared__ uint8_t  map3[32 * 256];       // (bucket2,byte3) -> bucket3
    __shared__ unsigned slotRes[32];          // residual rank within current bucket
    __shared__ unsigned slotBucket[32];       // current bucket id of each slot
    __shared__ unsigned slotKey[32];          // accumulated 32-bit key
    __shared__ unsigned slotByte[32];         // byte resolved at current level
    __shared__ int      nBucketsSh;

    const int tid  = threadIdx.x;
    const int lane = tid & 63;
    const int wave = tid >> 6;
    const int bid  = blockIdx.x;

    // ---- load 64 keys/thread into registers ----
    uint4 d[16];
    if (TRANSPOSED) {
        const uint4* src = (const uint4*)xt + (size_t)bid * (NN / 4);
#pragma unroll
        for (int j = 0; j < 16; ++j) d[j] = src[j * 1024 + tid];
    } else {
        int b = bid >> 6, c = bid & 63;
        const float* base = x + (size_t)b * NN * CC + c;
#pragma unroll
        for (int j = 0; j < 16; ++j) {
            unsigned v[4];
#pragma unroll
            for (int sub = 0; sub < 4; ++sub) {
                int n = (j * 4 + sub) * 1024 + tid;
                v[sub] = keyify(base[(size_t)n * CC]);
            }
            d[j] = make_uint4(v[0], v[1], v[2], v[3]);
        }
    }

    unsigned bkp[16];                         // packed per-value bucket cache (4 x u8)
#pragma unroll
    for (int j = 0; j < 16; ++j) bkp[j] = 0;

    // ---- init slots: ranks lo_i (s=2i), hi_i (s=2i+1), sorted ----
    if (tid < 32) {
        int i = tid >> 1;
        float idxf = ((float)(i + 1) * (1.0f / 17.0f)) * 65535.0f;
        int lo = (int)floorf(idxf);
        int hi = (int)ceilf(idxf);
        slotRes[tid]    = (unsigned)((tid & 1) ? hi : lo);
        slotBucket[tid] = 0;
        slotKey[tid]    = 0;
    }
    if (tid == 0) nBucketsSh = 1;
    for (int idx = tid; idx < 32 * 256; idx += 1024) HIST[idx] = 0;
    if (tid < 256) map1[tid] = 255;
    __syncthreads();

    for (int L = 1; L <= 4; ++L) {
        const int shCur  = 32 - 8 * L;        // byte_L position
        const int shPrev = 40 - 8 * L;        // byte_{L-1} position
        const uint8_t* mapPrev = (L == 2) ? map1 : (L == 3) ? map2 : map3;

        // ---- scan: histogram byte_L within live buckets ----
#pragma unroll
        for (int j = 0; j < 16; ++j) {
            unsigned w = bkp[j], nw = 0;
            unsigned vv[4] = { d[j].x, d[j].y, d[j].z, d[j].w };
#pragma unroll
            for (int sub = 0; sub < 4; ++sub) {
                unsigned v = vv[sub];
                unsigned bk = (w >> (8 * sub)) & 255u;
                if (L > 1) {
                    if (bk != 255u) bk = mapPrev[bk * 256 + ((v >> shPrev) & 255u)];
                }
                nw |= bk << (8 * sub);
                if (bk != 255u) atomicAdd(&HIST[bk * 256 + ((v >> shCur) & 255u)], 1u);
            }
            bkp[j] = nw;
        }
        __syncthreads();

        // ---- resolve: one wave per bucket, shuffle scan + ballot search ----
        int nB = nBucketsSh;
        for (int bucket = wave; bucket < nB; bucket += 16) {
            unsigned base = (unsigned)bucket * 256 + lane * 4;
            unsigned c0 = HIST[base], c1 = HIST[base + 1], c2 = HIST[base + 2], c3 = HIST[base + 3];
            unsigned sum4 = c0 + c1 + c2 + c3;
            unsigned incl = sum4;
#pragma unroll
            for (int off = 1; off < 64; off <<= 1) {
                unsigned t = __shfl_up(incl, off);
                if (lane >= off) incl += t;
            }
            unsigned cumStart = incl - sum4;  // exclusive prefix over 4-bin groups
            for (int s = 0; s < 32; ++s) {
                if ((int)slotBucket[s] != bucket) continue;   // wave-uniform
                unsigned r = slotRes[s];
                unsigned long long m = __ballot(cumStart <= r);
                int g = 63 - __clzll(m);
                if (lane == g) {
                    unsigned cc[4] = { c0, c1, c2, c3 };
                    unsigned cum = cumStart;
                    int jj = 0;
                    while (jj < 3 && cum + cc[jj] <= r) { cum += cc[jj]; ++jj; }
                    unsigned byte = (unsigned)(lane * 4 + jj);
                    slotByte[s] = byte;
                    slotRes[s]  = r - cum;
                    slotKey[s] |= byte << shCur;
                }
            }
        }
        __syncthreads();

        if (L < 4) {
            // ---- dedup (wave 0): renumber buckets, build map_L ----
            if (wave == 0) {
                int s = lane;
                unsigned pb = 0, by = 0;
                if (s < 32) { pb = slotBucket[s]; by = slotByte[s]; }
                unsigned pair  = (pb << 8) | by;
                unsigned prevp = __shfl_up(pair, 1);
                bool newf = (s < 32) && (s == 0 || pair != prevp);
                unsigned long long nm = __ballot(newf);
                uint8_t* mapCur = (L == 1) ? map1 : (L == 2) ? map2 : map3;
                if (s < 32) {
                    int nb = (int)__popcll(nm & ((1ULL << (s + 1)) - 1ULL)) - 1;
                    slotBucket[s] = (unsigned)nb;
                    if (newf) mapCur[pb * 256 + by] = (uint8_t)nb;
                }
                if (lane == 0) nBucketsSh = (int)__popcll(nm);
            }
            // ---- prep next level (concurrent with dedup; disjoint regions) ----
            for (int idx = tid; idx < 32 * 256; idx += 1024) HIST[idx] = 0;
            if (L == 1) { for (int idx = tid; idx < 32 * 256; idx += 1024) map2[idx] = 255; }
            if (L == 2) { for (int idx = tid; idx < 32 * 256; idx += 1024) map3[idx] = 255; }
            __syncthreads();
        }
    }

    // ---- epilogue: interpolate and write (B,C,Q) ----
    if (tid < QQ) {
        float idxf = ((float)(tid + 1) * (1.0f / 17.0f)) * 65535.0f;
        float frac = idxf - floorf(idxf);
        float vlo = unkeyify(slotKey[2 * tid]);
        float vhi = unkeyify(slotKey[2 * tid + 1]);
        out[(size_t)bid * QQ + tid] = vlo + (vhi - vlo) * frac;
    }
}

extern "C" void kernel_launch(void* const* d_in, const int* in_sizes, int n_in,
                              void* d_out, int out_size, void* d_ws, size_t ws_size,
                              hipStream_t stream) {
    const float* x = (const float*)d_in[0];
    float* out = (float*)d_out;
    const size_t need = (size_t)BB * CC * NN * sizeof(unsigned);  // 256 MiB

    if (ws_size >= need) {
        unsigned* xt = (unsigned*)d_ws;
        transpose_keyify<<<BB * (NN / 64), 256, 0, stream>>>(x, xt);
        radix_select<true><<<BB * CC, 1024, 0, stream>>>(xt, x, out);
    } else {
        // fallback: strided loads straight from the original layout (slow but correct)
        radix_select<false><<<BB * CC, 1024, 0, stream>>>(nullptr, x, out);
    }
}